// Round 4
// baseline (90.581 us; speedup 1.0000x reference)
//
#include <hip/hip_runtime.h>
#include <hip/hip_bf16.h>

constexpr int N = 16384;
constexpr int C = 64;     // NUM_CLUSTER
constexpr int D = 256;    // NUM_LATENT

// ---------------------------------------------------------------------------
// K0: ids[n] = argmax(mask[n,:]) via ballot. One wave per row.
// ---------------------------------------------------------------------------
__global__ __launch_bounds__(256) void ids_kernel(const float* __restrict__ mask,
                                                  int* __restrict__ ids) {
    const int w    = threadIdx.x >> 6;
    const int lane = threadIdx.x & 63;
    const int n    = blockIdx.x * 4 + w;
    const unsigned long long b = __ballot(mask[n * C + lane] > 0.5f);
    if (lane == 0) ids[n] = __ffsll(b) - 1;
}

// ---------------------------------------------------------------------------
// K1: per-chunk partial centroid sums into private LDS via ds_add_f32.
// lsum[id*256 + tid]: bank = tid%32 -> 2-way aliasing = free. One block per
// CU (P=256), streaming 64 rows; dump 64 KB coalesced at the end.
// ---------------------------------------------------------------------------
__global__ __launch_bounds__(256) void psum_kernel(const float* __restrict__ X,
                                                   const int* __restrict__ ids,
                                                   float* __restrict__ partials,
                                                   int* __restrict__ pcountT,
                                                   int P) {
    __shared__ float lsum[C * D];   // 64 KB
    __shared__ int   lcnt[C];
    const int tid  = threadIdx.x;
    const int p    = blockIdx.x;
    const int R    = N / P;
    const int row0 = p * R;

#pragma unroll
    for (int i = 0; i < (C * D) / (256 * 4); ++i)
        ((float4*)lsum)[tid + i * 256] = float4{0.f, 0.f, 0.f, 0.f};
    if (tid < C) lcnt[tid] = 0;
    __syncthreads();

#pragma unroll 4
    for (int r = 0; r < R; ++r) {
        const int n  = row0 + r;
        const int id = ids[n];                                   // uniform -> s_load
        atomicAdd(&lsum[id * D + tid], X[(size_t)n * D + tid]);  // ds_add_f32
        if (tid == 0) atomicAdd(&lcnt[id], 1);
    }
    __syncthreads();

    float* dst = partials + (size_t)p * (C * D);
#pragma unroll
    for (int i = 0; i < (C * D) / (256 * 4); ++i)
        ((float4*)dst)[tid + i * 256] = ((const float4*)lsum)[tid + i * 256];
    if (tid < C) pcountT[tid * P + p] = lcnt[tid];
}

// ---------------------------------------------------------------------------
// K2: muT[d][c] = (sum_p partials[p][c][d]) / count[c]. Block covers 64
// consecutive flat (c,d) pairs (c uniform per block since 64 | 256).
// Counts: all 256 threads load one partial count each (was lane-0-serial).
// ---------------------------------------------------------------------------
__global__ __launch_bounds__(256) void reduce_kernel(const float* __restrict__ partials,
                                                     const int* __restrict__ pcountT,
                                                     float* __restrict__ muT,
                                                     int P) {
    __shared__ float redf[4][64];
    __shared__ int   redi[4];
    const int tid  = threadIdx.x;
    const int w    = tid >> 6;
    const int lane = tid & 63;
    const int pair = blockIdx.x * 64 + lane;  // flat c*D + d
    const int c    = pair >> 8;               // uniform within block
    const int d    = pair & 255;

    float s = 0.f;
    for (int p = w; p < P; p += 4) s += partials[(size_t)p * (C * D) + pair];

    int ci = (tid < P) ? pcountT[c * P + tid] : 0;
#pragma unroll
    for (int off = 1; off < 64; off <<= 1) ci += __shfl_xor(ci, off, 64);

    redf[w][lane] = s;
    if (lane == 0) redi[w] = ci;
    __syncthreads();
    if (w == 0) {
        const float tot = redf[0][lane] + redf[1][lane] + redf[2][lane] + redf[3][lane];
        const int   cnt = redi[0] + redi[1] + redi[2] + redi[3];
        muT[d * C + c] = tot / (float)cnt;
    }
}

// ---------------------------------------------------------------------------
// K3: distances + soft assignment. lane = cluster; wave w owns dims
// [64w,64w+64) with mu in 64 registers. X staged through LDS:
//   - staging: wave w loads row w of the 4-row batch as lane-striped float4
//     (16 B/lane, perfectly coalesced, X read exactly once per block)
//   - compute: broadcast ds_read_b128 (same-address across lanes = no
//     conflict), 512 VALU per wave-batch -> VALU-bound
//   - ONE barrier per batch: xrow AND pd double-buffered; next-batch global
//     loads issued BEFORE compute, ds_write after (HBM latency hides under
//     ~1000 cy of VALU)
//   - finish: wave w normalizes row rb+w (all 4 waves busy)
// ---------------------------------------------------------------------------
constexpr int RPB = 16;

__global__ __launch_bounds__(256) void dist_kernel(const float* __restrict__ X,
                                                   const float* __restrict__ muT,
                                                   float* __restrict__ out) {
    __shared__ float xrow[2][4][D];    // 8 KB: [buf][row][dim]
    __shared__ float pd[2][4][4][C];   // 8 KB: [buf][writer_wave][row][cluster]

    const int tid  = threadIdx.x;
    const int w    = tid >> 6;
    const int lane = tid & 63;

    // mu chunk in registers: m[j] = mu[lane][64w+j] (lane-coalesced, L2-hot)
    float m[64];
    const float* muTw = muT + (w * 64) * C + lane;
#pragma unroll
    for (int j = 0; j < 64; ++j) m[j] = muTw[j * C];

    const int row0 = blockIdx.x * RPB;

    // stage batch 0: wave w loads row (row0 + w), lane-striped float4
    {
        const float4 st = *(const float4*)(X + (size_t)(row0 + w) * D + lane * 4);
        ((float4*)xrow[0][w])[lane] = st;
    }
    __syncthreads();

#pragma unroll 1
    for (int k = 0; k < RPB / 4; ++k) {
        const int buf = k & 1;
        const int rb  = row0 + k * 4;

        // issue next batch's global load early (T14 split)
        float4 nxt;
        if (k < RPB / 4 - 1)
            nxt = *(const float4*)(X + (size_t)(rb + 4 + w) * D + lane * 4);

        const float* x0 = xrow[buf][0] + w * 64;   // wave-uniform -> broadcast
        const float* x1 = xrow[buf][1] + w * 64;
        const float* x2 = xrow[buf][2] + w * 64;
        const float* x3 = xrow[buf][3] + w * 64;
        float a0 = 0.f, a1 = 0.f, a2 = 0.f, a3 = 0.f;
#pragma unroll
        for (int j4 = 0; j4 < 16; ++j4) {
            const float4 v0 = ((const float4*)x0)[j4];
            const float4 v1 = ((const float4*)x1)[j4];
            const float4 v2 = ((const float4*)x2)[j4];
            const float4 v3 = ((const float4*)x3)[j4];
            const float m0 = m[j4 * 4 + 0], m1 = m[j4 * 4 + 1];
            const float m2 = m[j4 * 4 + 2], m3 = m[j4 * 4 + 3];
            a0 += fabsf(v0.x - m0) + fabsf(v0.y - m1) + fabsf(v0.z - m2) + fabsf(v0.w - m3);
            a1 += fabsf(v1.x - m0) + fabsf(v1.y - m1) + fabsf(v1.z - m2) + fabsf(v1.w - m3);
            a2 += fabsf(v2.x - m0) + fabsf(v2.y - m1) + fabsf(v2.z - m2) + fabsf(v2.w - m3);
            a3 += fabsf(v3.x - m0) + fabsf(v3.y - m1) + fabsf(v3.z - m2) + fabsf(v3.w - m3);
        }

        // late LDS write of the prefetched batch (other buffer — no race with
        // this batch's reads; next batch's reads are after the barrier)
        if (k < RPB / 4 - 1)
            ((float4*)xrow[buf ^ 1][w])[lane] = nxt;

        pd[buf][w][0][lane] = a0;
        pd[buf][w][1][lane] = a1;
        pd[buf][w][2][lane] = a2;
        pd[buf][w][3][lane] = a3;
        __syncthreads();

        // finish: wave w owns row rb+w; next iteration writes pd[buf^1],
        // so no second barrier needed
        const float dist = pd[buf][0][w][lane] + pd[buf][1][w][lane]
                         + pd[buf][2][w][lane] + pd[buf][3][w][lane];
        const float q = 1.0f / (1.0f + dist);
        float ssum = q;
#pragma unroll
        for (int off = 1; off < 64; off <<= 1) ssum += __shfl_xor(ssum, off, 64);
        out[(size_t)(rb + w) * C + lane] = q / ssum;
    }
}

// ---------------------------------------------------------------------------
// Workspace layout (bytes):
//   [0,      65536)  : ids      16384 i32
//   [65536, 131072)  : muT      256*64 f32
//   [131072,196608)  : pcountT  64*PMAX i32
//   [196608, ...  )  : partials P*64*256 f32  (P picked from ws_size)
// No memsets: every buffer is fully written before it is read.
// ---------------------------------------------------------------------------
extern "C" void kernel_launch(void* const* d_in, const int* in_sizes, int n_in,
                              void* d_out, int out_size, void* d_ws, size_t ws_size,
                              hipStream_t stream) {
    const float* X    = (const float*)d_in[0];
    const float* mask = (const float*)d_in[1];
    float* out        = (float*)d_out;

    char*  ws       = (char*)d_ws;
    int*   ids      = (int*)(ws);
    float* muT      = (float*)(ws + 65536);
    int*   pcountT  = (int*)(ws + 131072);
    float* partials = (float*)(ws + 196608);

    const size_t base = 196608;
    const size_t slab = (size_t)C * D * 4;   // 64 KB per partial set
    int P = 2;
    if      (ws_size >= base + 256 * slab) P = 256;
    else if (ws_size >= base + 128 * slab) P = 128;
    else if (ws_size >= base + 32 * slab)  P = 32;
    else if (ws_size >= base + 8 * slab)   P = 8;

    ids_kernel   <<<N / 4,        256, 0, stream>>>(mask, ids);
    psum_kernel  <<<P,            256, 0, stream>>>(X, ids, partials, pcountT, P);
    reduce_kernel<<<(C * D) / 64, 256, 0, stream>>>(partials, pcountT, muT, P);
    dist_kernel  <<<N / RPB,      256, 0, stream>>>(X, muT, out);
}

// Round 5
// 81.149 us; speedup vs baseline: 1.1162x; 1.1162x over previous
//
#include <hip/hip_runtime.h>
#include <hip/hip_bf16.h>

constexpr int N = 16384;
constexpr int C = 64;     // NUM_CLUSTER
constexpr int D = 256;    // NUM_LATENT

// ---------------------------------------------------------------------------
// K0: ids[n] = argmax(mask[n,:]) via ballot. One wave per row.
// ---------------------------------------------------------------------------
__global__ __launch_bounds__(256) void ids_kernel(const float* __restrict__ mask,
                                                  int* __restrict__ ids) {
    const int w    = threadIdx.x >> 6;
    const int lane = threadIdx.x & 63;
    const int n    = blockIdx.x * 4 + w;
    const unsigned long long b = __ballot(mask[n * C + lane] > 0.5f);
    if (lane == 0) ids[n] = __ffsll(b) - 1;
}

// ---------------------------------------------------------------------------
// K1: per-chunk partial centroid sums into private LDS via ds_add_f32.
// lsum[id*256 + tid]: lanes consecutive -> 2-way bank aliasing = free.
// unroll 8 => 8 global loads in flight per wave (latency hiding at 1 wave/SIMD).
// ---------------------------------------------------------------------------
__global__ __launch_bounds__(256) void psum_kernel(const float* __restrict__ X,
                                                   const int* __restrict__ ids,
                                                   float* __restrict__ partials,
                                                   int* __restrict__ pcountT,
                                                   int P) {
    __shared__ float lsum[C * D];   // 64 KB
    __shared__ int   lcnt[C];
    const int tid  = threadIdx.x;
    const int p    = blockIdx.x;
    const int R    = N / P;
    const int row0 = p * R;

#pragma unroll
    for (int i = 0; i < (C * D) / (256 * 4); ++i)
        ((float4*)lsum)[tid + i * 256] = float4{0.f, 0.f, 0.f, 0.f};
    if (tid < C) lcnt[tid] = 0;
    __syncthreads();

#pragma unroll 8
    for (int r = 0; r < R; ++r) {
        const int n  = row0 + r;
        const int id = ids[n];                                   // uniform -> s_load
        atomicAdd(&lsum[id * D + tid], X[(size_t)n * D + tid]);  // ds_add_f32
        if (tid == 0) atomicAdd(&lcnt[id], 1);
    }
    __syncthreads();

    float* dst = partials + (size_t)p * (C * D);
#pragma unroll
    for (int i = 0; i < (C * D) / (256 * 4); ++i)
        ((float4*)dst)[tid + i * 256] = ((const float4*)lsum)[tid + i * 256];
    if (tid < C) pcountT[tid * P + p] = lcnt[tid];
}

// ---------------------------------------------------------------------------
// K2: mu[c][d] = (sum_p partials[p][c][d]) / count[c]   (natural [c][d] layout
// so dist's mu reads are wave-uniform scalar loads). 8 independent
// accumulators = 8 strided loads in flight (FP order change is fine).
// ---------------------------------------------------------------------------
__global__ __launch_bounds__(256) void reduce_kernel(const float* __restrict__ partials,
                                                     const int* __restrict__ pcountT,
                                                     float* __restrict__ mu,
                                                     int P) {
    __shared__ float redf[4][64];
    __shared__ int   redi[4];
    const int tid  = threadIdx.x;
    const int w    = tid >> 6;
    const int lane = tid & 63;
    const int pair = blockIdx.x * 64 + lane;  // flat c*D + d (c uniform: 64|256)
    const int c    = pair >> 8;

    const int Pw = P >> 2;                    // per-wave chunk of partial sets
    const float* base = partials + (size_t)(w * Pw) * (C * D) + pair;
    float s0=0,s1=0,s2=0,s3=0,s4=0,s5=0,s6=0,s7=0;
    int p = 0;
    for (; p + 8 <= Pw; p += 8) {
        s0 += base[(size_t)(p+0)*(C*D)];  s1 += base[(size_t)(p+1)*(C*D)];
        s2 += base[(size_t)(p+2)*(C*D)];  s3 += base[(size_t)(p+3)*(C*D)];
        s4 += base[(size_t)(p+4)*(C*D)];  s5 += base[(size_t)(p+5)*(C*D)];
        s6 += base[(size_t)(p+6)*(C*D)];  s7 += base[(size_t)(p+7)*(C*D)];
    }
    for (; p < Pw; ++p) s0 += base[(size_t)p*(C*D)];
    const float s = ((s0+s1)+(s2+s3)) + ((s4+s5)+(s6+s7));

    int ci = (tid < P) ? pcountT[c * P + tid] : 0;
#pragma unroll
    for (int off = 1; off < 64; off <<= 1) ci += __shfl_xor(ci, off, 64);

    redf[w][lane] = s;
    if (lane == 0) redi[w] = ci;
    __syncthreads();
    if (w == 0) {
        const float tot = redf[0][lane] + redf[1][lane] + redf[2][lane] + redf[3][lane];
        const int   cnt = redi[0] + redi[1] + redi[2] + redi[3];
        mu[pair] = tot / (float)cnt;
    }
}

// ---------------------------------------------------------------------------
// K3: distances + soft assignment, restructured (round-4 was LDS-port-bound:
// 4 waves x 64 broadcast ds_read_b128 per batch serialized at the CU LDS pipe,
// VALUBusy 38%).  New: lane = ROW, wave = 64-dim chunk.
//   - x: per-lane in 64 VGPRs (one row chunk), loaded once
//   - mu: wave-uniform -> SGPR s_loads, free as VALU operands
//   - inner loop: 64 clusters x 128 VALU, ZERO LDS traffic
//   - merge: one ds_add_f32 per cluster into pd[c][row] (lane-consecutive,
//     2-way bank = free; 64 LDS ops/wave total)
//   - finish: per-lane q, qsum (v_rcp), row store (L2 merges the stride)
// ---------------------------------------------------------------------------
__global__ __launch_bounds__(256) void dist_kernel(const float* __restrict__ X,
                                                   const float* __restrict__ mu,
                                                   float* __restrict__ out) {
    __shared__ float pd[C][64];   // [cluster][row] 16 KB
    const int tid  = threadIdx.x;
    const int w    = __builtin_amdgcn_readfirstlane(tid >> 6);  // uniform
    const int lane = tid & 63;
    const int row0 = blockIdx.x * 64;

    // zero pd (4 float4 per thread)
#pragma unroll
    for (int i = 0; i < 4; ++i)
        ((float4*)pd)[tid + i * 256] = float4{0.f, 0.f, 0.f, 0.f};

    // x chunk in registers: this lane's row, this wave's 64 dims
    float x[64];
    const float* xsrc = X + (size_t)(row0 + lane) * D + w * 64;
#pragma unroll
    for (int j = 0; j < 16; ++j) {
        const float4 v = ((const float4*)xsrc)[j];
        x[4*j+0] = v.x; x[4*j+1] = v.y; x[4*j+2] = v.z; x[4*j+3] = v.w;
    }
    __syncthreads();

    // per-cluster partial L1 distances (pure register VALU)
#pragma unroll 2
    for (int c = 0; c < C; ++c) {
        const float* mr = mu + c * D + w * 64;   // wave-uniform -> s_load
        float a0 = 0.f, a1 = 0.f, a2 = 0.f, a3 = 0.f;
#pragma unroll
        for (int j = 0; j < 16; ++j) {
            a0 += fabsf(x[4*j+0] - mr[4*j+0]);
            a1 += fabsf(x[4*j+1] - mr[4*j+1]);
            a2 += fabsf(x[4*j+2] - mr[4*j+2]);
            a3 += fabsf(x[4*j+3] - mr[4*j+3]);
        }
        atomicAdd(&pd[c][lane], (a0 + a1) + (a2 + a3));  // ds_add_f32, no rtn
    }
    __syncthreads();

    // finish: lane = row; q = 1/(1+dist), normalize, store row
    float q[C];
    float qsum = 0.f;
#pragma unroll
    for (int c = 0; c < C; ++c) {
        q[c] = __builtin_amdgcn_rcpf(1.0f + pd[c][lane]);
        qsum += q[c];
    }
    const float inv = __builtin_amdgcn_rcpf(qsum);
    float* orow = out + (size_t)(row0 + lane) * C;
#pragma unroll
    for (int k = 0; k < 16; ++k) {
        const float4 v{q[4*k+0]*inv, q[4*k+1]*inv, q[4*k+2]*inv, q[4*k+3]*inv};
        ((float4*)orow)[k] = v;
    }
}

// ---------------------------------------------------------------------------
// Workspace layout (bytes):
//   [0,      65536)  : ids      16384 i32
//   [65536, 131072)  : mu       64*256 f32 (natural [c][d])
//   [131072,196608)  : pcountT  64*256 i32
//   [196608, ...  )  : partials P*64*256 f32  (P picked from ws_size)
// No memsets: every buffer is fully written before it is read.
// ---------------------------------------------------------------------------
extern "C" void kernel_launch(void* const* d_in, const int* in_sizes, int n_in,
                              void* d_out, int out_size, void* d_ws, size_t ws_size,
                              hipStream_t stream) {
    const float* X    = (const float*)d_in[0];
    const float* mask = (const float*)d_in[1];
    float* out        = (float*)d_out;

    char*  ws       = (char*)d_ws;
    int*   ids      = (int*)(ws);
    float* mu       = (float*)(ws + 65536);
    int*   pcountT  = (int*)(ws + 131072);
    float* partials = (float*)(ws + 196608);

    const size_t base = 196608;
    const size_t slab = (size_t)C * D * 4;   // 64 KB per partial set
    int P = 4;
    if      (ws_size >= base + 256 * slab) P = 256;
    else if (ws_size >= base + 128 * slab) P = 128;
    else if (ws_size >= base + 32 * slab)  P = 32;
    else if (ws_size >= base + 8 * slab)   P = 8;

    ids_kernel   <<<N / 4,        256, 0, stream>>>(mask, ids);
    psum_kernel  <<<P,            256, 0, stream>>>(X, ids, partials, pcountT, P);
    reduce_kernel<<<(C * D) / 64, 256, 0, stream>>>(partials, pcountT, mu, P);
    dist_kernel  <<<N / 64,       256, 0, stream>>>(X, mu, out);
}

// Round 6
// 76.106 us; speedup vs baseline: 1.1902x; 1.0663x over previous
//
#include <hip/hip_runtime.h>
#include <hip/hip_bf16.h>

constexpr int N = 16384;
constexpr int C = 64;     // NUM_CLUSTER
constexpr int D = 256;    // NUM_LATENT

typedef float f32x4 __attribute__((ext_vector_type(4)));

// ---------------------------------------------------------------------------
// K1: ids (ballot) + per-chunk partial centroid sums into LDS via ds_add_f32.
// Block p owns rows [p*R,(p+1)*R). Main loop 4-row-batched (+unroll 2) so 8
// independent 1KB global loads are in flight per wave.
// ---------------------------------------------------------------------------
__global__ __launch_bounds__(256) void psum_kernel(const float* __restrict__ X,
                                                   const float* __restrict__ mask,
                                                   float* __restrict__ partials,
                                                   int* __restrict__ pcountT,
                                                   int P) {
    __shared__ float lsum[C * D];   // 64 KB
    __shared__ int   lid[4096];     // ids for this chunk (R <= 4096)
    __shared__ int   lcnt[C];
    const int tid  = threadIdx.x;
    const int w    = tid >> 6;
    const int lane = tid & 63;
    const int p    = blockIdx.x;
    const int R    = N / P;
    const int row0 = p * R;

#pragma unroll
    for (int i = 0; i < (C * D) / (256 * 4); ++i)
        ((f32x4*)lsum)[tid + i * 256] = f32x4{0.f, 0.f, 0.f, 0.f};
    if (tid < C) lcnt[tid] = 0;

    // ids: wave w handles rows w, w+4, ... (ballot over 64 clusters)
    for (int r = w; r < R; r += 4) {
        const unsigned long long b =
            __ballot(mask[(size_t)(row0 + r) * C + lane] > 0.5f);
        if (lane == 0) lid[r] = __ffsll(b) - 1;
    }
    __syncthreads();

    // chunk-local counts (LDS atomics, ~R/C contenders per address)
    for (int r = tid; r < R; r += 256) atomicAdd(&lcnt[lid[r]], 1);

    // main accumulation: 4-row batches, loads hoisted before the ds_adds
#pragma unroll 2
    for (int r = 0; r < R; r += 4) {
        const float v0 = X[(size_t)(row0 + r + 0) * D + tid];
        const float v1 = X[(size_t)(row0 + r + 1) * D + tid];
        const float v2 = X[(size_t)(row0 + r + 2) * D + tid];
        const float v3 = X[(size_t)(row0 + r + 3) * D + tid];
        const int i0 = lid[r + 0], i1 = lid[r + 1];
        const int i2 = lid[r + 2], i3 = lid[r + 3];
        atomicAdd(&lsum[i0 * D + tid], v0);   // ds_add_f32, no return
        atomicAdd(&lsum[i1 * D + tid], v1);
        atomicAdd(&lsum[i2 * D + tid], v2);
        atomicAdd(&lsum[i3 * D + tid], v3);
    }
    __syncthreads();

    float* dst = partials + (size_t)p * (C * D);
#pragma unroll
    for (int i = 0; i < (C * D) / (256 * 4); ++i)
        ((f32x4*)dst)[tid + i * 256] = ((const f32x4*)lsum)[tid + i * 256];
    if (tid < C) pcountT[tid * P + p] = lcnt[tid];
}

// ---------------------------------------------------------------------------
// K2: mu[c][d] = (sum_p partials[p][c][d]) / count[c].  16 independent
// accumulators -> 16 stride-64KB loads in flight per wave (latency-bound).
// ---------------------------------------------------------------------------
__global__ __launch_bounds__(256) void reduce_kernel(const float* __restrict__ partials,
                                                     const int* __restrict__ pcountT,
                                                     float* __restrict__ mu,
                                                     int P) {
    __shared__ float redf[4][64];
    __shared__ int   redi[4];
    const int tid  = threadIdx.x;
    const int w    = tid >> 6;
    const int lane = tid & 63;
    const int pair = blockIdx.x * 64 + lane;  // flat c*D + d (c uniform: 64|256)
    const int c    = pair >> 8;

    const int Pw = P >> 2;                    // per-wave chunk of partial sets
    const float* base = partials + (size_t)(w * Pw) * (C * D) + pair;
    float s[16];
#pragma unroll
    for (int i = 0; i < 16; ++i) s[i] = 0.f;
    int p = 0;
    for (; p + 16 <= Pw; p += 16) {
#pragma unroll
        for (int i = 0; i < 16; ++i) s[i] += base[(size_t)(p + i) * (C * D)];
    }
    for (; p < Pw; ++p) s[0] += base[(size_t)p * (C * D)];
#pragma unroll
    for (int st = 8; st >= 1; st >>= 1)
#pragma unroll
        for (int i = 0; i < st; ++i) s[i] += s[i + st];

    int ci = (tid < P) ? pcountT[c * P + tid] : 0;
#pragma unroll
    for (int off = 1; off < 64; off <<= 1) ci += __shfl_xor(ci, off, 64);

    redf[w][lane] = s[0];
    if (lane == 0) redi[w] = ci;
    __syncthreads();
    if (w == 0) {
        const float tot = redf[0][lane] + redf[1][lane] + redf[2][lane] + redf[3][lane];
        const int   cnt = redi[0] + redi[1] + redi[2] + redi[3];
        mu[pair] = tot / (float)cnt;
    }
}

// ---------------------------------------------------------------------------
// K3: distances + soft assignment. lane = ROW (64 rows/block), wave = 64-dim
// chunk. Round-5 failure: VGPR=40 proved the compiler rematerialized the x
// loads inside the c-loop (latency-bound). Fix: x in 16 NAMED f32x4 vars,
// pinned with an opaque asm def -> remat impossible. mu via uniform s_load
// (SGPR operands, proven working: round-5 SGPR=80). Inner loop = pure VALU.
// Finish split across waves (each owns 16 clusters), qsum merged via ds_add.
// ---------------------------------------------------------------------------
__global__ __launch_bounds__(256) void dist_kernel(const float* __restrict__ X,
                                                   const float* __restrict__ mu,
                                                   float* __restrict__ out) {
    __shared__ float pd[C][64];   // [cluster][row] 16 KB
    __shared__ float qsb[64];
    const int tid  = threadIdx.x;
    const int w    = __builtin_amdgcn_readfirstlane(tid >> 6);  // uniform
    const int lane = tid & 63;
    const int row0 = blockIdx.x * 64;

#pragma unroll
    for (int i = 0; i < 4; ++i)
        ((f32x4*)pd)[tid + i * 256] = f32x4{0.f, 0.f, 0.f, 0.f};
    if (tid < 64) qsb[tid] = 0.f;

    // x chunk: this lane's row, this wave's 64 dims — named vars + pin
    const f32x4* xs = (const f32x4*)(X + (size_t)(row0 + lane) * D + w * 64);
    f32x4 x0 = xs[0],  x1 = xs[1],  x2 = xs[2],  x3 = xs[3];
    f32x4 x4 = xs[4],  x5 = xs[5],  x6 = xs[6],  x7 = xs[7];
    f32x4 x8 = xs[8],  x9 = xs[9],  x10 = xs[10], x11 = xs[11];
    f32x4 x12 = xs[12], x13 = xs[13], x14 = xs[14], x15 = xs[15];
    asm volatile("" : "+v"(x0), "+v"(x1), "+v"(x2), "+v"(x3),
                      "+v"(x4), "+v"(x5), "+v"(x6), "+v"(x7),
                      "+v"(x8), "+v"(x9), "+v"(x10), "+v"(x11),
                      "+v"(x12), "+v"(x13), "+v"(x14), "+v"(x15));
    __syncthreads();

#define ACC4(xi, jb)                                                        \
    a0 += fabsf(xi.x - mr[(jb) + 0]); a1 += fabsf(xi.y - mr[(jb) + 1]);     \
    a2 += fabsf(xi.z - mr[(jb) + 2]); a3 += fabsf(xi.w - mr[(jb) + 3]);

#pragma unroll 2
    for (int c = 0; c < C; ++c) {
        const float* mr = mu + c * D + w * 64;   // uniform -> s_load
        float a0 = 0.f, a1 = 0.f, a2 = 0.f, a3 = 0.f;
        ACC4(x0, 0)   ACC4(x1, 4)   ACC4(x2, 8)   ACC4(x3, 12)
        ACC4(x4, 16)  ACC4(x5, 20)  ACC4(x6, 24)  ACC4(x7, 28)
        ACC4(x8, 32)  ACC4(x9, 36)  ACC4(x10, 40) ACC4(x11, 44)
        ACC4(x12, 48) ACC4(x13, 52) ACC4(x14, 56) ACC4(x15, 60)
        atomicAdd(&pd[c][lane], (a0 + a1) + (a2 + a3));  // ds_add_f32
    }
#undef ACC4
    __syncthreads();

    // finish: wave w owns clusters [16w, 16w+16); row = lane
    const int cb = w * 16;
    float qpart = 0.f;
#pragma unroll
    for (int j = 0; j < 16; ++j) {
        const float qq = __builtin_amdgcn_rcpf(1.0f + pd[cb + j][lane]);
        pd[cb + j][lane] = qq;     // own slot: no cross-thread hazard
        qpart += qq;
    }
    atomicAdd(&qsb[lane], qpart);  // ds_add, lanes consecutive
    __syncthreads();

    const float inv = __builtin_amdgcn_rcpf(qsb[lane]);
    float* orow = out + (size_t)(row0 + lane) * C;
#pragma unroll
    for (int k = 0; k < 4; ++k) {
        const int c0 = cb + 4 * k;
        const f32x4 v{pd[c0 + 0][lane] * inv, pd[c0 + 1][lane] * inv,
                      pd[c0 + 2][lane] * inv, pd[c0 + 3][lane] * inv};
        ((f32x4*)orow)[(cb >> 2) + k] = v;   // lane's 64B slice, rows contiguous
    }
}

// ---------------------------------------------------------------------------
// Workspace layout (bytes):
//   [65536, 131072)  : mu       64*256 f32 (natural [c][d])
//   [131072,196608)  : pcountT  64*256 i32
//   [196608, ...  )  : partials P*64*256 f32  (P picked from ws_size)
// No memsets: every buffer is fully written before it is read.
// ---------------------------------------------------------------------------
extern "C" void kernel_launch(void* const* d_in, const int* in_sizes, int n_in,
                              void* d_out, int out_size, void* d_ws, size_t ws_size,
                              hipStream_t stream) {
    const float* X    = (const float*)d_in[0];
    const float* mask = (const float*)d_in[1];
    float* out        = (float*)d_out;

    char*  ws       = (char*)d_ws;
    float* mu       = (float*)(ws + 65536);
    int*   pcountT  = (int*)(ws + 131072);
    float* partials = (float*)(ws + 196608);

    const size_t base = 196608;
    const size_t slab = (size_t)C * D * 4;   // 64 KB per partial set
    int P = 4;
    if      (ws_size >= base + 256 * slab) P = 256;
    else if (ws_size >= base + 128 * slab) P = 128;
    else if (ws_size >= base + 32 * slab)  P = 32;
    else if (ws_size >= base + 8 * slab)   P = 8;

    psum_kernel  <<<P,            256, 0, stream>>>(X, mask, partials, pcountT, P);
    reduce_kernel<<<(C * D) / 64, 256, 0, stream>>>(partials, pcountT, mu, P);
    dist_kernel  <<<N / 64,       256, 0, stream>>>(X, mu, out);
}

// Round 7
// 66.331 us; speedup vs baseline: 1.3656x; 1.1474x over previous
//
#include <hip/hip_runtime.h>
#include <hip/hip_bf16.h>

constexpr int N = 16384;
constexpr int C = 64;     // NUM_CLUSTER
constexpr int D = 256;    // NUM_LATENT

typedef float f32x4 __attribute__((ext_vector_type(4)));

// ---------------------------------------------------------------------------
// K1: ids (ballot) + per-chunk partial centroid sums into LDS via ds_add_f32.
// Block p owns rows [p*R,(p+1)*R). 4-row batches (+unroll 2) -> 8 independent
// global loads in flight per wave. (unchanged from round 6)
// ---------------------------------------------------------------------------
__global__ __launch_bounds__(256) void psum_kernel(const float* __restrict__ X,
                                                   const float* __restrict__ mask,
                                                   float* __restrict__ partials,
                                                   int* __restrict__ pcountT,
                                                   int P) {
    __shared__ float lsum[C * D];   // 64 KB
    __shared__ int   lid[4096];     // ids for this chunk (R <= 4096)
    __shared__ int   lcnt[C];
    const int tid  = threadIdx.x;
    const int w    = tid >> 6;
    const int lane = tid & 63;
    const int p    = blockIdx.x;
    const int R    = N / P;
    const int row0 = p * R;

#pragma unroll
    for (int i = 0; i < (C * D) / (256 * 4); ++i)
        ((f32x4*)lsum)[tid + i * 256] = f32x4{0.f, 0.f, 0.f, 0.f};
    if (tid < C) lcnt[tid] = 0;

    // ids: wave w handles rows w, w+4, ... (ballot over 64 clusters)
    for (int r = w; r < R; r += 4) {
        const unsigned long long b =
            __ballot(mask[(size_t)(row0 + r) * C + lane] > 0.5f);
        if (lane == 0) lid[r] = __ffsll(b) - 1;
    }
    __syncthreads();

    for (int r = tid; r < R; r += 256) atomicAdd(&lcnt[lid[r]], 1);

#pragma unroll 2
    for (int r = 0; r < R; r += 4) {
        const float v0 = X[(size_t)(row0 + r + 0) * D + tid];
        const float v1 = X[(size_t)(row0 + r + 1) * D + tid];
        const float v2 = X[(size_t)(row0 + r + 2) * D + tid];
        const float v3 = X[(size_t)(row0 + r + 3) * D + tid];
        const int i0 = lid[r + 0], i1 = lid[r + 1];
        const int i2 = lid[r + 2], i3 = lid[r + 3];
        atomicAdd(&lsum[i0 * D + tid], v0);   // ds_add_f32, no return
        atomicAdd(&lsum[i1 * D + tid], v1);
        atomicAdd(&lsum[i2 * D + tid], v2);
        atomicAdd(&lsum[i3 * D + tid], v3);
    }
    __syncthreads();

    float* dst = partials + (size_t)p * (C * D);
#pragma unroll
    for (int i = 0; i < (C * D) / (256 * 4); ++i)
        ((f32x4*)dst)[tid + i * 256] = ((const f32x4*)lsum)[tid + i * 256];
    if (tid < C) pcountT[tid * P + p] = lcnt[tid];
}

// ---------------------------------------------------------------------------
// K2: muT[d][c] = (sum_p partials[p][c][d]) / count[c].  16 independent
// accumulators -> 16 stride-64KB coalesced loads in flight per wave.
// NOW WRITES TRANSPOSED muT (dist's per-lane mu load wants [d][c]).
// ---------------------------------------------------------------------------
__global__ __launch_bounds__(256) void reduce_kernel(const float* __restrict__ partials,
                                                     const int* __restrict__ pcountT,
                                                     float* __restrict__ muT,
                                                     int P) {
    __shared__ float redf[4][64];
    __shared__ int   redi[4];
    const int tid  = threadIdx.x;
    const int w    = tid >> 6;
    const int lane = tid & 63;
    const int pair = blockIdx.x * 64 + lane;  // flat c*D + d (c uniform: 64|256)
    const int c    = pair >> 8;
    const int d    = pair & 255;

    const int Pw = P >> 2;                    // per-wave chunk of partial sets
    const float* base = partials + (size_t)(w * Pw) * (C * D) + pair;
    float s[16];
#pragma unroll
    for (int i = 0; i < 16; ++i) s[i] = 0.f;
    int p = 0;
    for (; p + 16 <= Pw; p += 16) {
#pragma unroll
        for (int i = 0; i < 16; ++i) s[i] += base[(size_t)(p + i) * (C * D)];
    }
    for (; p < Pw; ++p) s[0] += base[(size_t)p * (C * D)];
#pragma unroll
    for (int st = 8; st >= 1; st >>= 1)
#pragma unroll
        for (int i = 0; i < st; ++i) s[i] += s[i + st];

    int ci = (tid < P) ? pcountT[c * P + tid] : 0;
#pragma unroll
    for (int off = 1; off < 64; off <<= 1) ci += __shfl_xor(ci, off, 64);

    redf[w][lane] = s[0];
    if (lane == 0) redi[w] = ci;
    __syncthreads();
    if (w == 0) {
        const float tot = redf[0][lane] + redf[1][lane] + redf[2][lane] + redf[3][lane];
        const int   cnt = redi[0] + redi[1] + redi[2] + redi[3];
        muT[d * C + c] = tot / (float)cnt;    // transposed store (L2 merges)
    }
}

// ---------------------------------------------------------------------------
// K3: distances + soft assignment, role-swapped + high-TLP.
// Rounds 4-6 all hit ~41/36 us: <=1 wave/SIMD with a per-iteration latency
// chain (mu re-s_loaded every cluster iteration at 1 block/CU).
// New: lane = CLUSTER, wave = 64-dim chunk, block = 16 rows, grid = 1024
// (4 blocks/CU, ~4-5 waves/SIMD):
//   - mu: LOOP-INVARIANT, per-lane in 64 pinned VGPRs (one coalesced load
//     from muT per wave lifetime; asm pin forbids remat — round-5 lesson)
//   - x: wave-uniform row -> s_load f32x4 (SGPR operand, free in VALU)
//   - inner: 128 VALU per row, zero LDS, zero VMEM
//   - merge: 1 ds_add_f32 per row per wave into pd[16][64] (2-way = free)
//   - finish: wave w owns rows 4w..4w+3; shfl-reduce; coalesced 256B stores
// ---------------------------------------------------------------------------
__global__ __launch_bounds__(256) void dist_kernel(const float* __restrict__ X,
                                                   const float* __restrict__ muT,
                                                   float* __restrict__ out) {
    __shared__ float pd[16][C];   // [row][cluster] 4 KB
    const int tid  = threadIdx.x;
    const int w    = __builtin_amdgcn_readfirstlane(tid >> 6);  // uniform
    const int lane = tid & 63;
    const int row0 = blockIdx.x * 16;

    ((f32x4*)pd)[tid] = f32x4{0.f, 0.f, 0.f, 0.f};   // zero all 1024 floats

    // mu chunk: m[j] = mu[cluster=lane][dim=w*64+j] = muT[(w*64+j)*C + lane]
    float m[64];
    const float* mbase = muT + (w * 64) * C + lane;
#pragma unroll
    for (int j = 0; j < 64; ++j) m[j] = mbase[j * C];
#define PIN16(b) asm volatile("" : "+v"(m[b+0]), "+v"(m[b+1]), "+v"(m[b+2]),   \
    "+v"(m[b+3]), "+v"(m[b+4]), "+v"(m[b+5]), "+v"(m[b+6]), "+v"(m[b+7]),      \
    "+v"(m[b+8]), "+v"(m[b+9]), "+v"(m[b+10]), "+v"(m[b+11]), "+v"(m[b+12]),   \
    "+v"(m[b+13]), "+v"(m[b+14]), "+v"(m[b+15]))
    PIN16(0); PIN16(16); PIN16(32); PIN16(48);
#undef PIN16
    __syncthreads();

#pragma unroll 1
    for (int r = 0; r < 16; ++r) {
        const f32x4* xr = (const f32x4*)(X + (size_t)(row0 + r) * D + w * 64);
        float a0 = 0.f, a1 = 0.f, a2 = 0.f, a3 = 0.f;
#pragma unroll
        for (int j = 0; j < 16; ++j) {
            const f32x4 xv = xr[j];          // uniform addr -> s_load_dwordx4
            a0 += fabsf(xv.x - m[4*j+0]);
            a1 += fabsf(xv.y - m[4*j+1]);
            a2 += fabsf(xv.z - m[4*j+2]);
            a3 += fabsf(xv.w - m[4*j+3]);
        }
        atomicAdd(&pd[r][lane], (a0 + a1) + (a2 + a3));  // ds_add_f32
    }
    __syncthreads();

    // finish: wave w owns rows 4w .. 4w+3
#pragma unroll
    for (int i = 0; i < 4; ++i) {
        const int r = 4 * w + i;
        const float q = __builtin_amdgcn_rcpf(1.0f + pd[r][lane]);
        float s = q;
#pragma unroll
        for (int off = 1; off < 64; off <<= 1) s += __shfl_xor(s, off, 64);
        out[(size_t)(row0 + r) * C + lane] = q * __builtin_amdgcn_rcpf(s);
    }
}

// ---------------------------------------------------------------------------
// Workspace layout (bytes):
//   [65536, 131072)  : muT      256*64 f32 ([d][c])
//   [131072,196608)  : pcountT  64*256 i32
//   [196608, ...  )  : partials P*64*256 f32  (P picked from ws_size)
// No memsets: every buffer is fully written before it is read.
// ---------------------------------------------------------------------------
extern "C" void kernel_launch(void* const* d_in, const int* in_sizes, int n_in,
                              void* d_out, int out_size, void* d_ws, size_t ws_size,
                              hipStream_t stream) {
    const float* X    = (const float*)d_in[0];
    const float* mask = (const float*)d_in[1];
    float* out        = (float*)d_out;

    char*  ws       = (char*)d_ws;
    float* muT      = (float*)(ws + 65536);
    int*   pcountT  = (int*)(ws + 131072);
    float* partials = (float*)(ws + 196608);

    const size_t base = 196608;
    const size_t slab = (size_t)C * D * 4;   // 64 KB per partial set
    int P = 4;
    if      (ws_size >= base + 256 * slab) P = 256;
    else if (ws_size >= base + 128 * slab) P = 128;
    else if (ws_size >= base + 32 * slab)  P = 32;
    else if (ws_size >= base + 8 * slab)   P = 8;

    psum_kernel  <<<P,            256, 0, stream>>>(X, mask, partials, pcountT, P);
    reduce_kernel<<<(C * D) / 64, 256, 0, stream>>>(partials, pcountT, muT, P);
    dist_kernel  <<<N / 16,       256, 0, stream>>>(X, muT, out);
}